// Round 1
// baseline (165.197 us; speedup 1.0000x reference)
//
#include <hip/hip_runtime.h>

typedef unsigned short u16;
typedef short bf16x8 __attribute__((ext_vector_type(8)));
typedef float f32x4 __attribute__((ext_vector_type(4)));

#define BATCH   16384
#define INDIM   1024
#define KNEUR   1024

__device__ __forceinline__ u16 f2bf(float f) {
  union { float f; unsigned u; } v; v.f = f;
  unsigned r = v.u + 0x7FFFu + ((v.u >> 16) & 1u);   // RNE
  return (u16)(r >> 16);
}
__device__ __forceinline__ float bf2f(u16 h) {
  union { unsigned u; float f; } v; v.u = ((unsigned)h) << 16; return v.f;
}

#define GLDS(gp, lp) __builtin_amdgcn_global_load_lds( \
  (const __attribute__((address_space(1))) void*)(gp), \
  (__attribute__((address_space(3))) void*)(lp), 16, 0, 0)

// ---------------- x -> bf16 + row sq-norm ----------------
__global__ void k_conv_x(const float* __restrict__ x, u16* __restrict__ xb,
                         float* __restrict__ x2) {
  int b = blockIdx.x;
  int t = threadIdx.x;
  const float4 v = *(const float4*)(x + (size_t)b * INDIM + t * 4);
  u16 o0 = f2bf(v.x), o1 = f2bf(v.y), o2 = f2bf(v.z), o3 = f2bf(v.w);
  ushort4 o; o.x = o0; o.y = o1; o.z = o2; o.w = o3;
  *(ushort4*)(xb + (size_t)b * INDIM + t * 4) = o;
  float s = v.x * v.x + v.y * v.y + v.z * v.z + v.w * v.w;
  for (int m = 32; m; m >>= 1) s += __shfl_xor(s, m, 64);
  __shared__ float ws_[4];
  if ((t & 63) == 0) ws_[t >> 6] = s;
  __syncthreads();
  if (t == 0) x2[b] = ws_[0] + ws_[1] + ws_[2] + ws_[3];
}

// ---------------- W -> W^T bf16 ----------------
__global__ void k_trans_w(const float* __restrict__ w, u16* __restrict__ wt) {
  __shared__ float tile[64][65];
  int bi = blockIdx.x & 15;   // k-tile (cols of W)
  int bj = blockIdx.x >> 4;   // i-tile (rows of W)
  int tx = threadIdx.x & 63, ty = threadIdx.x >> 6;
  int i0 = bj * 64, k0 = bi * 64;
  for (int r = ty; r < 64; r += 4)
    tile[r][tx] = w[(size_t)(i0 + r) * KNEUR + k0 + tx];
  __syncthreads();
  for (int r = ty; r < 64; r += 4)
    wt[(size_t)(k0 + r) * INDIM + i0 + tx] = f2bf(tile[tx][r]);
}

// ---------------- column sq-norms of W (exact f32) ----------------
__global__ void k_w2(const float* __restrict__ w, float* __restrict__ w2) {
  int tx = threadIdx.x & 63, ty = threadIdx.x >> 6;
  int k = blockIdx.x * 64 + tx;
  float s = 0.f;
  for (int i = ty * 256; i < ty * 256 + 256; ++i) {
    float v = w[(size_t)i * KNEUR + k];
    s += v * v;
  }
  __shared__ float red[4][64];
  red[ty][tx] = s;
  __syncthreads();
  if (ty == 0) w2[k] = red[0][tx] + red[1][tx] + red[2][tx] + red[3][tx];
}

// ---------------- neighborhood table T[c][k] ----------------
__global__ void k_T(const int* __restrict__ loc, const int* __restrict__ itp,
                    u16* __restrict__ Tb, float* __restrict__ Tf) {
  int id = blockIdx.x * 256 + threadIdx.x;    // c*1024 + k
  int c = id >> 10, k = id & 1023;
  float corr = 1.f - (float)itp[0] / 100.f;
  float lr = 0.3f * corr;
  float sig = 16.f * corr;
  float inv_s2 = 1.f / (sig * sig);
  int di = loc[2 * c] - loc[2 * k];
  int dj = loc[2 * c + 1] - loc[2 * k + 1];
  float v = lr * __expf(-(float)(di * di + dj * dj) * inv_s2);
  Tf[id] = v;
  Tb[id] = f2bf(v);
}

// ---------------- MFMA GEMM, both operands [row][k] bf16, k-len 1024 -------
// EPI=1: distance + min/argmin epilogue (GEMM1)
// EPI=0: weight-update epilogue (GEMM2)
template <int EPI>
__global__ __launch_bounds__(256, 2)
void k_gemm(const u16* __restrict__ A, const u16* __restrict__ Bm,
            const float* __restrict__ x2, const float* __restrict__ w2,
            float* __restrict__ pmin, int* __restrict__ pidx,
            const float* __restrict__ Wf, const float* __restrict__ S,
            float* __restrict__ outw) {
  __shared__ __align__(16) u16 ldsA[128 * 64];
  __shared__ __align__(16) u16 ldsB[128 * 64];
  __shared__ float s_rv[2][128];
  __shared__ int   s_ri[2][128];

  int bid = blockIdx.x;
  int mb, nb;
  if (EPI == 1) {
    int swz = (bid & 7) * 128 + (bid >> 3);   // XCD-contiguous sample panels
    mb = swz >> 3; nb = swz & 7;
  } else {
    mb = bid >> 3; nb = bid & 7;
  }
  int lane = threadIdx.x & 63;
  int wid = threadIdx.x >> 6;
  int wr = wid >> 1, wc = wid & 1;

  f32x4 acc[4][4];
  #pragma unroll
  for (int i = 0; i < 4; ++i)
    #pragma unroll
    for (int j = 0; j < 4; ++j) { acc[i][j][0] = 0.f; acc[i][j][1] = 0.f; acc[i][j][2] = 0.f; acc[i][j][3] = 0.f; }

  const size_t rowA0 = (size_t)mb * 128;
  const size_t rowB0 = (size_t)nb * 128;

  for (int kt = 0; kt < 16; ++kt) {
    int k0 = kt * 64;
    __syncthreads();
    #pragma unroll
    for (int q = 0; q < 4; ++q) {
      int p = q * 256 + wid * 64 + lane;
      int row = p >> 3;
      int clog = (p & 7) ^ (row & 7);          // inverse-swizzled global source
      GLDS(A + (rowA0 + row) * 1024 + k0 + clog * 8,
           ldsA + (size_t)(q * 256 + wid * 64) * 8);
    }
    #pragma unroll
    for (int q = 0; q < 4; ++q) {
      int p = q * 256 + wid * 64 + lane;
      int row = p >> 3;
      int clog = (p & 7) ^ (row & 7);
      GLDS(Bm + (rowB0 + row) * 1024 + k0 + clog * 8,
           ldsB + (size_t)(q * 256 + wid * 64) * 8);
    }
    __syncthreads();
    #pragma unroll
    for (int kk = 0; kk < 2; ++kk) {
      bf16x8 af[4], bfr[4];
      #pragma unroll
      for (int mt = 0; mt < 4; ++mt) {
        int row = wr * 64 + mt * 16 + (lane & 15);
        int ch = (kk * 4 + (lane >> 4)) ^ (row & 7);   // swizzled read
        af[mt] = *(const bf16x8*)(ldsA + row * 64 + ch * 8);
      }
      #pragma unroll
      for (int nt = 0; nt < 4; ++nt) {
        int row = wc * 64 + nt * 16 + (lane & 15);
        int ch = (kk * 4 + (lane >> 4)) ^ (row & 7);
        bfr[nt] = *(const bf16x8*)(ldsB + row * 64 + ch * 8);
      }
      #pragma unroll
      for (int mt = 0; mt < 4; ++mt)
        #pragma unroll
        for (int nt = 0; nt < 4; ++nt)
          acc[mt][nt] = __builtin_amdgcn_mfma_f32_16x16x32_bf16(af[mt], bfr[nt], acc[mt][nt], 0, 0, 0);
    }
  }

  if (EPI == 1) {
    int g = lane >> 4;
    int li = lane & 15;
    #pragma unroll
    for (int mt = 0; mt < 4; ++mt) {
      #pragma unroll
      for (int r = 0; r < 4; ++r) {
        int rowl = wr * 64 + mt * 16 + g * 4 + r;
        float xv = x2[rowA0 + rowl];
        float v = 1e30f; int vi = 0;
        #pragma unroll
        for (int nt = 0; nt < 4; ++nt) {
          int col = (int)rowB0 + wc * 64 + nt * 16 + li;
          float d2 = xv + w2[col] - 2.f * acc[mt][nt][r];
          if (d2 < v) { v = d2; vi = col; }
        }
        #pragma unroll
        for (int m = 1; m < 16; m <<= 1) {
          float ov = __shfl_xor(v, m, 64);
          int oi = __shfl_xor(vi, m, 64);
          if (ov < v || (ov == v && oi < vi)) { v = ov; vi = oi; }
        }
        if (li == 0) { s_rv[wc][rowl] = v; s_ri[wc][rowl] = vi; }
      }
    }
    __syncthreads();
    int t = threadIdx.x;
    if (t < 128) {
      float v0 = s_rv[0][t], v1 = s_rv[1][t];
      int i0 = s_ri[0][t], i1 = s_ri[1][t];
      float v = v0; int vi = i0;
      if (v1 < v0) { v = v1; vi = i1; }   // tie keeps lower col (wc=0)
      size_t brow = rowA0 + t;
      pmin[brow * 8 + nb] = v;
      pidx[brow * 8 + nb] = vi;
    }
  } else {
    const float invB = 1.f / (float)BATCH;
    #pragma unroll
    for (int mt = 0; mt < 4; ++mt)
      #pragma unroll
      for (int nt = 0; nt < 4; ++nt)
        #pragma unroll
        for (int r = 0; r < 4; ++r) {
          int i = (int)rowA0 + wr * 64 + mt * 16 + (lane >> 4) * 4 + r;
          int k = (int)rowB0 + wc * 64 + nt * 16 + (lane & 15);
          float wv = Wf[(size_t)i * KNEUR + k];
          float P = acc[mt][nt][r];
          outw[(size_t)i * KNEUR + k] = wv + (P - wv * S[k]) * invB;
        }
  }
}

// ---------------- BMU reduce + loss partials ----------------
__global__ void k_bmu(const float* __restrict__ pmin, const int* __restrict__ pidx,
                      int* __restrict__ bmu, float* __restrict__ lpart) {
  int b = blockIdx.x * 256 + threadIdx.x;
  float v = 1e30f; int vi = 0;
  #pragma unroll
  for (int j = 0; j < 8; ++j) {
    float pv = pmin[(size_t)b * 8 + j];
    if (pv < v) { v = pv; vi = pidx[(size_t)b * 8 + j]; }
  }
  bmu[b] = vi;
  float d = sqrtf(fmaxf(v, 0.f));
  __shared__ float red[256];
  red[threadIdx.x] = d;
  __syncthreads();
  for (int s = 128; s > 0; s >>= 1) {
    if (threadIdx.x < s) red[threadIdx.x] += red[threadIdx.x + s];
    __syncthreads();
  }
  if (threadIdx.x == 0) lpart[blockIdx.x] = red[0];
}

__global__ void k_loss(const float* __restrict__ lpart, float* __restrict__ out) {
  if (threadIdx.x == 0) {
    float s = 0.f;
    for (int i = 0; i < 64; ++i) s += lpart[i];
    out[0] = s * (1.f / (float)BATCH);
  }
}

// ---------------- class-bucketed Xsum^T (bf16), deterministic ----------------
__global__ __launch_bounds__(256)
void k_xsum(const int* __restrict__ bmu, const u16* __restrict__ xb,
            u16* __restrict__ xst, float* __restrict__ cntf) {
  int c = blockIdx.x;
  int t = threadIdx.x;
  __shared__ u16 list[BATCH];
  __shared__ int scan[256];
  __shared__ int s_total;
  int cnt = 0;
  for (int j = 0; j < 64; ++j) cnt += (bmu[j * 256 + t] == c);
  scan[t] = cnt;
  __syncthreads();
  for (int off = 1; off < 256; off <<= 1) {
    int v = scan[t];
    int va = (t >= off) ? scan[t - off] : 0;
    __syncthreads();
    scan[t] = v + va;
    __syncthreads();
  }
  int pos = scan[t] - cnt;   // exclusive prefix
  if (t == 255) s_total = scan[255];
  __syncthreads();
  int total = s_total;
  for (int j = 0; j < 64; ++j) {
    int b = j * 256 + t;
    if (bmu[b] == c) list[pos++] = (u16)b;
  }
  __syncthreads();
  float a0 = 0.f, a1 = 0.f, a2 = 0.f, a3 = 0.f;
  for (int m = 0; m < total; ++m) {
    int b = list[m];
    ushort4 v = *(const ushort4*)(xb + (size_t)b * INDIM + t * 4);
    a0 += bf2f(v.x); a1 += bf2f(v.y); a2 += bf2f(v.z); a3 += bf2f(v.w);
  }
  xst[(size_t)(4 * t + 0) * KNEUR + c] = f2bf(a0);
  xst[(size_t)(4 * t + 1) * KNEUR + c] = f2bf(a1);
  xst[(size_t)(4 * t + 2) * KNEUR + c] = f2bf(a2);
  xst[(size_t)(4 * t + 3) * KNEUR + c] = f2bf(a3);
  if (t == 0) cntf[c] = (float)total;
}

// ---------------- S[k] = sum_c cnt[c]*T[c][k], two-stage deterministic -------
__global__ void k_spart(const float* __restrict__ cntf, const float* __restrict__ Tf,
                        float* __restrict__ spart) {
  int cchunk = blockIdx.x >> 2;
  int kb = blockIdx.x & 3;
  int k = kb * 256 + threadIdx.x;
  float s = 0.f;
  for (int c = cchunk * 64; c < cchunk * 64 + 64; ++c)
    s += cntf[c] * Tf[(size_t)c * KNEUR + k];
  spart[cchunk * KNEUR + k] = s;
}
__global__ void k_sfinal(const float* __restrict__ spart, float* __restrict__ S) {
  int k = blockIdx.x * 256 + threadIdx.x;
  float s = 0.f;
  #pragma unroll
  for (int j = 0; j < 16; ++j) s += spart[j * KNEUR + k];
  S[k] = s;
}

extern "C" void kernel_launch(void* const* d_in, const int* in_sizes, int n_in,
                              void* d_out, int out_size, void* d_ws, size_t ws_size,
                              hipStream_t stream) {
  const float* x = (const float*)d_in[0];
  const float* w = (const float*)d_in[1];
  const int* loc = (const int*)d_in[2];
  const int* it = (const int*)d_in[3];
  float* out = (float*)d_out;

  char* ws = (char*)d_ws;
  size_t off = 0;
  auto alloc = [&](size_t bytes) -> void* {
    void* p = ws + off;
    off += (bytes + 255) & ~(size_t)255;
    return p;
  };
  u16* xb    = (u16*)  alloc((size_t)BATCH * INDIM * 2);
  u16* wt    = (u16*)  alloc((size_t)KNEUR * INDIM * 2);
  u16* Tb    = (u16*)  alloc((size_t)KNEUR * KNEUR * 2);
  float* Tf  = (float*)alloc((size_t)KNEUR * KNEUR * 4);
  u16* xst   = (u16*)  alloc((size_t)INDIM * KNEUR * 2);
  float* x2  = (float*)alloc((size_t)BATCH * 4);
  float* w2  = (float*)alloc((size_t)KNEUR * 4);
  float* pmin= (float*)alloc((size_t)BATCH * 8 * 4);
  int* pidx  = (int*)  alloc((size_t)BATCH * 8 * 4);
  int* bmu   = (int*)  alloc((size_t)BATCH * 4);
  float* cntf= (float*)alloc((size_t)KNEUR * 4);
  float* spart=(float*)alloc((size_t)16 * KNEUR * 4);
  float* S   = (float*)alloc((size_t)KNEUR * 4);
  float* lpart=(float*)alloc(64 * 4);
  if (off > ws_size) return;  // workspace too small — fail loudly via wrong output

  k_conv_x<<<BATCH, 256, 0, stream>>>(x, xb, x2);
  k_trans_w<<<256, 256, 0, stream>>>(w, wt);
  k_w2<<<16, 256, 0, stream>>>(w, w2);
  k_T<<<4096, 256, 0, stream>>>(loc, it, Tb, Tf);
  k_gemm<1><<<1024, 256, 0, stream>>>(xb, wt, x2, w2, pmin, pidx, nullptr, nullptr, nullptr);
  k_bmu<<<64, 256, 0, stream>>>(pmin, pidx, bmu, lpart);
  k_loss<<<1, 64, 0, stream>>>(lpart, out);
  k_xsum<<<1024, 256, 0, stream>>>(bmu, xb, xst, cntf);
  k_spart<<<64, 256, 0, stream>>>(cntf, Tf, spart);
  k_sfinal<<<4, 256, 0, stream>>>(spart, S);
  k_gemm<0><<<64, 256, 0, stream>>>(xst, Tb, nullptr, nullptr, nullptr, nullptr, w, S, out + 1);
}